// Round 10
// baseline (210.261 us; speedup 1.0000x reference)
//
#include <hip/hip_runtime.h>
#include <hip/hip_fp16.h>

#define HD 16

static constexpr int NN = 100000;   // nodes
static constexpr int EE = 3200000;  // edges (before self-loops)
static constexpr int GG = 1000;     // graphs
static constexpr int ET = EE + NN;  // edges incl. self-loops
static constexpr float NEG = 0.2f;  // leaky_relu slope
static constexpr float LOG2E = 1.44269504f;

static constexpr int BSH = 8;                       // 256 nodes per bucket
static constexpr int NB = (NN + 255) >> BSH;        // 391 buckets
static constexpr int EPB = 8192;                    // edges per block (bucket passes)
static constexpr int GB = (ET + EPB - 1) / EPB;     // 403 blocks
static constexpr int ITER = EPB / 1024;             // 8 edges per thread

__device__ __forceinline__ int imin(int a, int b) { return a < b ? a : b; }

__device__ __forceinline__ float h2f(unsigned short u) {
  __half_raw r; r.x = u;
  return __half2float((__half)r);
}

// ---- DPP helpers (within 16-lane rows) ----
template <int N>
__device__ __forceinline__ float row_ror_add(float v) {
  int m = __builtin_amdgcn_update_dpp(0, __float_as_int(v), 0x120 + N, 0xF, 0xF, true);
  return v + __int_as_float(m);
}
// quad sum via quad_perm: [1,0,3,2]=0xB1, [2,3,0,1]=0x4E
__device__ __forceinline__ float quad_sum(float v) {
  int a = __builtin_amdgcn_update_dpp(0, __float_as_int(v), 0xB1, 0xF, 0xF, true);
  v += __int_as_float(a);
  int b = __builtin_amdgcn_update_dpp(0, __float_as_int(v), 0x4E, 0xF, 0xF, true);
  return v + __int_as_float(b);
}
// sum over the 4 slots of a 16-lane row (slot = lane distance 4)
__device__ __forceinline__ float slot_sum16(float v) {
  v = row_ror_add<4>(v);
  v = row_ror_add<8>(v);
  return v;
}

// ---------- pass A: coarse histogram (LDS-aggregated) ----------
__global__ void k_chist(const int* __restrict__ edst, int* __restrict__ chist) {
  __shared__ int sh[NB];
  int t = threadIdx.x;
  for (int i = t; i < NB; i += 1024) sh[i] = 0;
  __syncthreads();
  int b0 = blockIdx.x * EPB;
#pragma unroll
  for (int i = 0; i < ITER; ++i) {
    int e = b0 + t + i * 1024;
    if (e < ET) {
      int d = (e < EE) ? edst[e] : e - EE;  // self-loop block appended at end
      atomicAdd(&sh[d >> BSH], 1);
    }
  }
  __syncthreads();
  for (int i = t; i < NB; i += 1024)
    if (sh[i]) atomicAdd(&chist[i], sh[i]);
}

// ---------- scan coarse histogram -> bucket bases ----------
__global__ void k_cscan(const int* __restrict__ chist, int* __restrict__ cbase,
                        int* __restrict__ ccur, int* __restrict__ rowptr) {
  __shared__ int sh[512];
  int t = threadIdx.x;
  sh[t] = (t < NB) ? chist[t] : 0;
  __syncthreads();
  for (int off = 1; off < 512; off <<= 1) {
    int v = sh[t];
    int a = (t >= off) ? sh[t - off] : 0;
    __syncthreads();
    sh[t] = v + a;
    __syncthreads();
  }
  if (t < NB) {
    int b = (t == 0) ? 0 : sh[t - 1];
    cbase[t] = b;
    ccur[t] = b;
  }
  if (t == 0) rowptr[NN] = ET;
}

// ---------- pass B: scatter packed records into coarse bucket regions ----------
// record = (dst & 255) << 17 | src   (src < 2^17, local dst < 2^8 -> 25 bits)
__global__ void k_csplit(const int* __restrict__ esrc, const int* __restrict__ edst,
                         int* __restrict__ ccur, unsigned* __restrict__ tmp) {
  __shared__ int hist[NB];
  __shared__ int base[NB];
  int t = threadIdx.x;
  for (int i = t; i < NB; i += 1024) hist[i] = 0;
  __syncthreads();
  int b0 = blockIdx.x * EPB;
  int sl[ITER], dl[ITER];
#pragma unroll
  for (int i = 0; i < ITER; ++i) {
    int e = b0 + t + i * 1024;
    int s = -1, d = 0;
    if (e < ET) {
      if (e < EE) { s = esrc[e]; d = edst[e]; } else { s = e - EE; d = s; }
      atomicAdd(&hist[d >> BSH], 1);
    }
    sl[i] = s; dl[i] = d;
  }
  __syncthreads();
  for (int i = t; i < NB; i += 1024) {
    int c = hist[i];
    base[i] = c ? atomicAdd(&ccur[i], c) : 0;  // one reservation per bucket per block
    hist[i] = 0;                               // reuse as running counter
  }
  __syncthreads();
#pragma unroll
  for (int i = 0; i < ITER; ++i) {
    int s = sl[i];
    if (s >= 0) {
      int d = dl[i], bb = d >> BSH;
      int slot = base[bb] + atomicAdd(&hist[bb], 1);
      tmp[slot] = ((unsigned)(d & 255) << 17) | (unsigned)s;
    }
  }
}

// ---------- pass C: per-bucket fine counting sort -> rowptr + psrc ----------
__global__ void k_fsort(const unsigned* __restrict__ tmp, const int* __restrict__ cbase,
                        const int* __restrict__ chist, int* __restrict__ rowptr,
                        int* __restrict__ psrc) {
  __shared__ int fh[256];
  __shared__ int fs[256];
  int b = blockIdx.x, t = threadIdx.x;
  if (t < 256) fh[t] = 0;
  __syncthreads();
  int beg = cbase[b], cnt = chist[b];
  for (int i = t; i < cnt; i += 1024)
    atomicAdd(&fh[tmp[beg + i] >> 17], 1);
  __syncthreads();
  if (t < 256) fs[t] = fh[t];
  __syncthreads();
  for (int off = 1; off < 256; off <<= 1) {
    int v = 0, a = 0;
    if (t < 256) { v = fs[t]; if (t >= off) a = fs[t - off]; }
    __syncthreads();
    if (t < 256) fs[t] = v + a;
    __syncthreads();
  }
  if (t < 256) {
    int ex = fs[t] - fh[t];  // exclusive within bucket
    fs[t] = ex;              // becomes the running placement counter
    int node = (b << BSH) + t;
    if (node < NN) rowptr[node] = beg + ex;
  }
  __syncthreads();
  for (int i = t; i < cnt; i += 1024) {
    unsigned v = tmp[beg + i];
    int ld = v >> 17;
    psrc[beg + atomicAdd(&fs[ld], 1)] = (int)(v & 0x1FFFFu);
  }
}

// ---------- fold inter-layer linear into next projections: Wc = W@P, bc = b@P + bp ----------
__global__ void k_comb(const float* __restrict__ W0, const float* __restrict__ b0,
                       const float* __restrict__ Wl1, const float* __restrict__ bl1,
                       const float* __restrict__ Wr1, const float* __restrict__ br1,
                       const float* __restrict__ W1, const float* __restrict__ b1,
                       const float* __restrict__ Wl2, const float* __restrict__ bl2,
                       const float* __restrict__ Wr2, const float* __restrict__ br2,
                       float* __restrict__ Wc0l, float* __restrict__ bc0l,
                       float* __restrict__ Wc0r, float* __restrict__ bc0r,
                       float* __restrict__ Wc1l, float* __restrict__ bc1l,
                       float* __restrict__ Wc1r, float* __restrict__ bc1r) {
  const float *W, *b, *P, *bp;
  float *Wo, *bo;
  switch (blockIdx.x) {
    case 0:  W = W0; b = b0; P = Wl1; bp = bl1; Wo = Wc0l; bo = bc0l; break;
    case 1:  W = W0; b = b0; P = Wr1; bp = br1; Wo = Wc0r; bo = bc0r; break;
    case 2:  W = W1; b = b1; P = Wl2; bp = bl2; Wo = Wc1l; bo = bc1l; break;
    default: W = W1; b = b1; P = Wr2; bp = br2; Wo = Wc1r; bo = bc1r; break;
  }
  int t = threadIdx.x;  // 256
  int c = t >> 4, k = t & 15;
  float s = 0.f;
#pragma unroll
  for (int i = 0; i < 16; ++i) s = fmaf(W[c * 16 + i], P[i * 16 + k], s);
  Wo[t] = s;
  if (t < 16) {
    float sb = bp[t];
#pragma unroll
    for (int i = 0; i < 16; ++i) sb = fmaf(b[i], P[i * 16 + t], sb);
    bo[t] = sb;
  }
}

// ---------- fused conv layer: TWO nodes per wave, value-prefetch pipeline ----------
// Half = 32 lanes = 8 edge-slots x 4 feature-quads. Register double-buffer:
// iteration N issues the gathers for iteration N+1 (indices prefetched 2 ahead)
// and computes on registers loaded in iteration N-1 -> gather latency hides
// under compute + TLP instead of stalling every iteration.
// MODE 0 = first (xl/xr rank-1 from x), 1 = mid, 2 = last (pool).
template <int MODE>
__global__ void k_conv(const int* __restrict__ rowptr, const int* __restrict__ psrc,
                       const float* __restrict__ x,
                       const float* __restrict__ Wl0, const float* __restrict__ bl0,
                       const float* __restrict__ Wr0, const float* __restrict__ br0,
                       const __half* __restrict__ xlh, const float* __restrict__ xr,
                       const float* __restrict__ att, const float* __restrict__ cbias,
                       const float* __restrict__ Wcl, const float* __restrict__ bcl,
                       const float* __restrict__ Wcr, const float* __restrict__ bcr,
                       const float* __restrict__ Wlast, const float* __restrict__ blast,
                       __half* __restrict__ oxlh, float* __restrict__ oxr,
                       float* __restrict__ gpool, const int* __restrict__ batch) {
  __shared__ float hsh[4][2][16];
  int gt = blockIdx.x * blockDim.x + threadIdx.x;
  int wave = gt >> 6;
  int lane = threadIdx.x & 63;
  int hf = lane >> 5;        // which node of the pair
  int lane5 = lane & 31;
  int ei = lane5 >> 2;       // edge slot 0..7
  int q = lane & 3;          // feature quad
  int n = wave * 2 + hf;
  if (n >= NN) return;
  int k0 = q * 4;
  float4 att4 = *reinterpret_cast<const float4*>(att + k0);
  att4.x *= LOG2E; att4.y *= LOG2E; att4.z *= LOG2E; att4.w *= LOG2E;
  float4 xr4, wl4, bl4;
  if constexpr (MODE == 0) {
    wl4 = *reinterpret_cast<const float4*>(Wl0 + k0);
    bl4 = *reinterpret_cast<const float4*>(bl0 + k0);
    float4 wr4 = *reinterpret_cast<const float4*>(Wr0 + k0);
    float4 br4 = *reinterpret_cast<const float4*>(br0 + k0);
    float xn = x[n];
    xr4.x = fmaf(xn, wr4.x, br4.x);
    xr4.y = fmaf(xn, wr4.y, br4.y);
    xr4.z = fmaf(xn, wr4.z, br4.z);
    xr4.w = fmaf(xn, wr4.w, br4.w);
  } else {
    xr4 = *reinterpret_cast<const float4*>(xr + (size_t)n * HD + k0);
  }
  int beg = rowptr[n], end = rowptr[n + 1];
  int e1 = end - 1;
  int p = beg + ei;
  // pipeline prologue: iter-0 values + iter-1 indices
  int i0 = psrc[imin(p, e1)];
  int i1 = psrc[imin(p + 8, e1)];
  float cx0, cx1;
  ushort4 cr0, cr1;
  if constexpr (MODE == 0) {
    cx0 = x[i0]; cx1 = x[i1];
  } else {
    cr0 = *reinterpret_cast<const ushort4*>(xlh + (size_t)i0 * HD + k0);
    cr1 = *reinterpret_cast<const ushort4*>(xlh + (size_t)i1 * HD + k0);
  }
  int t0 = psrc[imin(p + 16, e1)];
  int t1 = psrc[imin(p + 24, e1)];
  float l0 = 0.f, l1 = 0.f;
  float a00 = 0.f, a01 = 0.f, a02 = 0.f, a03 = 0.f;
  float a10 = 0.f, a11 = 0.f, a12 = 0.f, a13 = 0.f;
  for (; p < end; p += 16) {
    // issue NEXT iteration's value gathers (indices already in hand)...
    float nx0, nx1;
    ushort4 nr0, nr1;
    if constexpr (MODE == 0) {
      nx0 = x[t0]; nx1 = x[t1];
    } else {
      nr0 = *reinterpret_cast<const ushort4*>(xlh + (size_t)t0 * HD + k0);
      nr1 = *reinterpret_cast<const ushort4*>(xlh + (size_t)t1 * HD + k0);
    }
    // ...and the indices two iterations out
    int u0 = psrc[imin(p + 32, e1)];
    int u1 = psrc[imin(p + 40, e1)];
    // compute on CURRENT values (in registers since last iteration)
    float x00, x01, x02, x03, x10, x11, x12, x13;
    if constexpr (MODE == 0) {
      x00 = fmaf(cx0, wl4.x, bl4.x); x01 = fmaf(cx0, wl4.y, bl4.y);
      x02 = fmaf(cx0, wl4.z, bl4.z); x03 = fmaf(cx0, wl4.w, bl4.w);
      x10 = fmaf(cx1, wl4.x, bl4.x); x11 = fmaf(cx1, wl4.y, bl4.y);
      x12 = fmaf(cx1, wl4.z, bl4.z); x13 = fmaf(cx1, wl4.w, bl4.w);
    } else {
      x00 = h2f(cr0.x); x01 = h2f(cr0.y); x02 = h2f(cr0.z); x03 = h2f(cr0.w);
      x10 = h2f(cr1.x); x11 = h2f(cr1.y); x12 = h2f(cr1.z); x13 = h2f(cr1.w);
    }
    float u, sp0 = 0.f, sp1 = 0.f;
    u = x00 + xr4.x; u = fmaxf(u, NEG * u); sp0 = fmaf(u, att4.x, sp0);
    u = x01 + xr4.y; u = fmaxf(u, NEG * u); sp0 = fmaf(u, att4.y, sp0);
    u = x02 + xr4.z; u = fmaxf(u, NEG * u); sp0 = fmaf(u, att4.z, sp0);
    u = x03 + xr4.w; u = fmaxf(u, NEG * u); sp0 = fmaf(u, att4.w, sp0);
    u = x10 + xr4.x; u = fmaxf(u, NEG * u); sp1 = fmaf(u, att4.x, sp1);
    u = x11 + xr4.y; u = fmaxf(u, NEG * u); sp1 = fmaf(u, att4.y, sp1);
    u = x12 + xr4.z; u = fmaxf(u, NEG * u); sp1 = fmaf(u, att4.z, sp1);
    u = x13 + xr4.w; u = fmaxf(u, NEG * u); sp1 = fmaf(u, att4.w, sp1);
    float sc0 = quad_sum(sp0);
    float sc1 = quad_sum(sp1);
    float pe0 = __builtin_amdgcn_exp2f(sc0);
    float pe1 = (p + 8 < end) ? __builtin_amdgcn_exp2f(sc1) : 0.f;
    l0 += pe0;
    a00 = fmaf(pe0, x00, a00); a01 = fmaf(pe0, x01, a01);
    a02 = fmaf(pe0, x02, a02); a03 = fmaf(pe0, x03, a03);
    l1 += pe1;
    a10 = fmaf(pe1, x10, a10); a11 = fmaf(pe1, x11, a11);
    a12 = fmaf(pe1, x12, a12); a13 = fmaf(pe1, x13, a13);
    // rotate pipeline registers
    if constexpr (MODE == 0) { cx0 = nx0; cx1 = nx1; }
    else { cr0 = nr0; cr1 = nr1; }
    t0 = u0; t1 = u1;
  }
  float l = l0 + l1;
  float b0 = a00 + a10, b1 = a01 + a11, b2 = a02 + a12, b3 = a03 + a13;
  // slot reduce within each 16-row (DPP), then cross-row within the half (DS)
  l = slot_sum16(l);
  b0 = slot_sum16(b0); b1 = slot_sum16(b1);
  b2 = slot_sum16(b2); b3 = slot_sum16(b3);
  l += __shfl_xor(l, 16, 64);
  b0 += __shfl_xor(b0, 16, 64);
  b1 += __shfl_xor(b1, 16, 64);
  b2 += __shfl_xor(b2, 16, 64);
  b3 += __shfl_xor(b3, 16, 64);
  float rl = __builtin_amdgcn_rcpf(l);
  float4 cb4 = *reinterpret_cast<const float4*>(cbias + k0);
  float h0 = fmaxf(fmaf(b0, rl, cb4.x), 0.f);
  float h1 = fmaxf(fmaf(b1, rl, cb4.y), 0.f);
  float h2 = fmaxf(fmaf(b2, rl, cb4.z), 0.f);
  float h3 = fmaxf(fmaf(b3, rl, cb4.w), 0.f);
  // publish h to LDS (quad lanes of slot 0 hold the full 16 features)
  int w = threadIdx.x >> 6;
  if (lane5 < 4)
    *reinterpret_cast<float4*>(&hsh[w][hf][lane5 * 4]) = make_float4(h0, h1, h2, h3);
  int sub = lane5 >> 4;      // 0 or 1
  int k = lane5 & 15;
  const float* hrow = hsh[w][hf];
  if constexpr (MODE == 2) {
    // o = h @ Wlast (+ blast): sub-split rows, xor-16 combine
    float o = 0.f;
#pragma unroll
    for (int i = 0; i < 8; ++i) {
      int c = 8 * sub + i;
      o = fmaf(hrow[c], Wlast[c * HD + k], o);
    }
    o += __shfl_xor(o, 16, 64);
    if (sub == 0) atomicAdd(gpool + (size_t)batch[n] * HD + k, o + blast[k]);
  } else {
    // sub0 computes full xl2 (Wcl), sub1 computes full xr2 (Wcr) in parallel
    const float* Wsel = sub ? Wcr : Wcl;
    float o = 0.f;
#pragma unroll
    for (int c = 0; c < 16; ++c) o = fmaf(hrow[c], Wsel[c * HD + k], o);
    if (sub == 0) oxlh[(size_t)n * HD + k] = __float2half(o + bcl[k]);
    else          oxr[(size_t)n * HD + k] = o + bcr[k];
  }
}

// ---------- graph-level MLP head: [G,16] -> [G,1] ----------
__global__ void k_mlp(const float* __restrict__ g,
                      const float* __restrict__ W0, const float* __restrict__ b0,
                      const float* __restrict__ W1, const float* __restrict__ b1,
                      const float* __restrict__ W2, const float* __restrict__ b2,
                      float* __restrict__ out) {
  int gi = blockIdx.x * blockDim.x + threadIdx.x;
  if (gi >= GG) return;
  float v[HD], a[HD];
  const float4* g4 = reinterpret_cast<const float4*>(g + (size_t)gi * HD);
#pragma unroll
  for (int i = 0; i < 4; ++i) {
    float4 tv = g4[i];
    v[4 * i] = tv.x; v[4 * i + 1] = tv.y; v[4 * i + 2] = tv.z; v[4 * i + 3] = tv.w;
  }
#pragma unroll
  for (int j = 0; j < HD; ++j) {
    float s = b0[j];
#pragma unroll
    for (int kk = 0; kk < HD; ++kk) s = fmaf(v[kk], W0[kk * HD + j], s);
    a[j] = s > 0.f ? s : 0.f;
  }
#pragma unroll
  for (int j = 0; j < HD; ++j) {
    float s = b1[j];
#pragma unroll
    for (int kk = 0; kk < HD; ++kk) s = fmaf(a[kk], W1[kk * HD + j], s);
    v[j] = s > 0.f ? s : 0.f;
  }
  float s = b2[0];
#pragma unroll
  for (int kk = 0; kk < HD; ++kk) s = fmaf(v[kk], W2[kk], s);
  out[gi] = s;
}

extern "C" void kernel_launch(void* const* d_in, const int* in_sizes, int n_in,
                              void* d_out, int out_size, void* d_ws, size_t ws_size,
                              hipStream_t stream) {
  const float* x = (const float*)d_in[0];
  const int* ei = (const int*)d_in[1];  // [2, EE] int32
  const int* batch = (const int*)d_in[2];
  const int* esrc = ei;
  const int* edst = ei + EE;

  const float* cW[3][6];  // Wl bl Wr br att bias
  const float* lW[3][2];  // W b
  int i = 3;
  for (int l = 0; l < 3; ++l) {
    for (int j = 0; j < 6; ++j) cW[l][j] = (const float*)d_in[i++];
    lW[l][0] = (const float*)d_in[i++];
    lW[l][1] = (const float*)d_in[i++];
  }
  const float *oW[3], *ob[3];
  for (int j = 0; j < 3; ++j) {
    oW[j] = (const float*)d_in[i++];
    ob[j] = (const float*)d_in[i++];
  }

  // workspace carve-up (~33 MB), 256B-aligned slices
  char* ws = (char*)d_ws;
  size_t off = 0;
  auto alloc = [&](size_t bytes) {
    void* p = ws + off;
    off = (off + bytes + 255) & ~(size_t)255;
    return p;
  };
  int* psrc = (int*)alloc((size_t)ET * 4);
  int* rowptr = (int*)alloc((size_t)(NN + 1) * 4);
  int* chist = (int*)alloc((size_t)NB * 4);
  int* cbase = (int*)alloc((size_t)NB * 4);
  int* ccur = (int*)alloc((size_t)NB * 4);
  float* Wc0l = (float*)alloc(256 * 4);
  float* Wc0r = (float*)alloc(256 * 4);
  float* Wc1l = (float*)alloc(256 * 4);
  float* Wc1r = (float*)alloc(256 * 4);
  float* bc0l = (float*)alloc(16 * 4);
  float* bc0r = (float*)alloc(16 * 4);
  float* bc1l = (float*)alloc(16 * 4);
  float* bc1r = (float*)alloc(16 * 4);
  // union region: tmp (ET*4 = 13.2MB) dead after k_fsort; feature buffers
  // (2x half 3.2MB + 2x f32 6.4MB + gbuf 64KB = 19.3MB) written only after.
  size_t NNHD = (size_t)NN * HD;
  size_t featBytes = NNHD * 12 + (size_t)GG * HD * 4;
  size_t uniBytes = (size_t)ET * 4 > featBytes ? (size_t)ET * 4 : featBytes;
  char* uni = (char*)alloc(uniBytes);
  unsigned* tmp = (unsigned*)uni;
  __half* xlhB = (__half*)uni;
  float* xrB = (float*)(uni + NNHD * 2);
  __half* xlhA = (__half*)(uni + NNHD * 6);
  float* xrA = (float*)(uni + NNHD * 8);
  float* gbuf = (float*)(uni + NNHD * 12);

  const int B = 256;
  const int gConv = (NN * 32 + B - 1) / B;  // HALF-wave per node (2 nodes/wave)
  const int gMlp = (GG + B - 1) / B;

  hipMemsetAsync(chist, 0, (size_t)NB * 4, stream);

  // tiny weight-fold kernel (independent of CSR; overlaps it)
  k_comb<<<4, 256, 0, stream>>>(lW[0][0], lW[0][1],
                                cW[1][0], cW[1][1], cW[1][2], cW[1][3],
                                lW[1][0], lW[1][1],
                                cW[2][0], cW[2][1], cW[2][2], cW[2][3],
                                Wc0l, bc0l, Wc0r, bc0r, Wc1l, bc1l, Wc1r, bc1r);

  // CSR build: all per-edge atomics in LDS
  k_chist<<<GB, 1024, 0, stream>>>(edst, chist);
  k_cscan<<<1, 512, 0, stream>>>(chist, cbase, ccur, rowptr);
  k_csplit<<<GB, 1024, 0, stream>>>(esrc, edst, ccur, tmp);
  k_fsort<<<NB, 1024, 0, stream>>>(tmp, cbase, chist, rowptr, psrc);

  // gbuf zero AFTER tmp is dead (aliases the same region)
  hipMemsetAsync(gbuf, 0, (size_t)GG * HD * 4, stream);

  // three fused conv layers
  k_conv<0><<<gConv, B, 0, stream>>>(rowptr, psrc, x,
                                     cW[0][0], cW[0][1], cW[0][2], cW[0][3],
                                     nullptr, nullptr, cW[0][4], cW[0][5],
                                     Wc0l, bc0l, Wc0r, bc0r, nullptr, nullptr,
                                     xlhB, xrB, nullptr, nullptr);
  k_conv<1><<<gConv, B, 0, stream>>>(rowptr, psrc, nullptr,
                                     nullptr, nullptr, nullptr, nullptr,
                                     xlhB, xrB, cW[1][4], cW[1][5],
                                     Wc1l, bc1l, Wc1r, bc1r, nullptr, nullptr,
                                     xlhA, xrA, nullptr, nullptr);
  k_conv<2><<<gConv, B, 0, stream>>>(rowptr, psrc, nullptr,
                                     nullptr, nullptr, nullptr, nullptr,
                                     xlhA, xrA, cW[2][4], cW[2][5],
                                     nullptr, nullptr, nullptr, nullptr,
                                     lW[2][0], lW[2][1],
                                     nullptr, nullptr, gbuf, batch);

  k_mlp<<<gMlp, B, 0, stream>>>(gbuf, oW[0], ob[0], oW[1], ob[1], oW[2], ob[2],
                                (float*)d_out);
}